// Round 1
// baseline (5324.965 us; speedup 1.0000x reference)
//
#include <hip/hip_runtime.h>
#include <hip/hip_bf16.h>

typedef short bf16x8 __attribute__((ext_vector_type(8)));
typedef float f32x4 __attribute__((ext_vector_type(4)));

// ---------------- prep: Mcat = [Wf;Wb] @ proj_w  (512x256 bf16), cvec = W@proj_b + b ----
__global__ __launch_bounds__(256) void prep_mcat(
    const float* __restrict__ proj_w, const float* __restrict__ proj_b,
    const float* __restrict__ Wf, const float* __restrict__ bf_,
    const float* __restrict__ Wb, const float* __restrict__ bb_,
    __hip_bfloat16* __restrict__ Mcat, float* __restrict__ cvec)
{
    int n = blockIdx.x;       // 0..511
    int c = threadIdx.x;      // 0..255
    const float* W    = (n < 256) ? (Wf + n * 256) : (Wb + (n - 256) * 256);
    const float* bias = (n < 256) ? bf_ : bb_;
    float acc = 0.f;
    for (int k = 0; k < 256; ++k)
        acc = fmaf(W[k], proj_w[k * 256 + c], acc);
    Mcat[n * 256 + c] = __float2bfloat16(acc);

    __shared__ float red[256];
    red[c] = W[c] * proj_b[c];
    __syncthreads();
    for (int s = 128; s > 0; s >>= 1) {
        if (c < s) red[c] += red[c + s];
        __syncthreads();
    }
    if (c == 0) cvec[n] = red[0] + bias[n & 255];
}

// ---------------- prep: W1cat (1536x512 bf16), b1cat, W2pad (128x1536 bf16 block-diag), b2cat
__global__ __launch_bounds__(256) void prep_weights(
    const float* __restrict__ cls_w1, const float* __restrict__ cls_b1,
    const float* __restrict__ cls_w2, const float* __restrict__ cls_b2,
    const float* __restrict__ reg_w1, const float* __restrict__ reg_b1,
    const float* __restrict__ reg_w2, const float* __restrict__ reg_b2,
    const float* __restrict__ ctr_w1, const float* __restrict__ ctr_b1,
    const float* __restrict__ ctr_w2, const float* __restrict__ ctr_b2,
    __hip_bfloat16* __restrict__ W1cat, float* __restrict__ b1cat,
    __hip_bfloat16* __restrict__ W2pad, float* __restrict__ b2cat)
{
    int idx = blockIdx.x * 256 + threadIdx.x;
    if (idx < 786432) { // W1cat 1536*512
        int n = idx >> 9, k = idx & 511;
        const float* src = (n < 512) ? cls_w1 : (n < 1024 ? reg_w1 : ctr_w1);
        int nn = n & 511;
        W1cat[idx] = __float2bfloat16(src[nn * 512 + k]);
    }
    if (idx < 196608) { // W2pad 128x1536
        int j = idx / 1536, k = idx % 1536;
        float v = 0.f;
        if (j < 80 && k < 512)                         v = cls_w2[j * 512 + k];
        else if (j >= 80 && j < 84 && k >= 512 && k < 1024) v = reg_w2[(j - 80) * 512 + (k - 512)];
        else if (j == 84 && k >= 1024)                 v = ctr_w2[k - 1024];
        W2pad[idx] = __float2bfloat16(v);
    }
    if (idx < 1536)
        b1cat[idx] = (idx < 512) ? cls_b1[idx] : (idx < 1024 ? reg_b1[idx - 512] : ctr_b1[idx - 1024]);
    if (idx < 96)
        b2cat[idx] = (idx < 80) ? cls_b2[idx] : (idx < 84 ? reg_b2[idx - 80] : (idx == 84 ? ctr_b2[0] : 0.f));
}

// ---------------- feat (B,C,H,W) f32 -> fx (B*S, C) bf16 (transpose) -----------------
__global__ __launch_bounds__(256) void transpose_feat(
    const float* __restrict__ feat, __hip_bfloat16* __restrict__ fx)
{
    __shared__ float tile[32][65];
    int st = blockIdx.x * 64, ct = blockIdx.y * 32, b = blockIdx.z;
    int tid = threadIdx.x;
    int sl = tid & 63, cl = tid >> 6;  // 64 s, 4 c per pass
    const float* fp = feat + ((size_t)b * 256 + ct) * 4096 + st;
#pragma unroll
    for (int i = 0; i < 8; ++i)
        tile[cl + i * 4][sl] = fp[(size_t)(cl + i * 4) * 4096 + sl];
    __syncthreads();
    int cw = tid & 31, sw = tid >> 5;  // 32 c, 8 s per pass
    __hip_bfloat16* op = fx + ((size_t)(b * 4096 + st)) * 256 + ct;
#pragma unroll
    for (int i = 0; i < 8; ++i)
        op[(size_t)(sw + i * 8) * 256 + cw] = __float2bfloat16(tile[cw][sw + i * 8]);
}

// ---------------- generic bf16 MFMA GEMM: C[M,N] = A[M,K] * B[N,K]^T --------------------
// MODE 0: f32 out. MODE 1: f32 out + bias[col]. MODE 2: bf16 out, relu(x + bias[col]).
template <int MODE>
__global__ __launch_bounds__(256) void gemm_bf16(
    const __hip_bfloat16* __restrict__ A, const __hip_bfloat16* __restrict__ B,
    void* __restrict__ Cv, const float* __restrict__ bias, int M, int N, int K)
{
    __shared__ short As[128][48];
    __shared__ short Bs[64][48];
    const int tid = threadIdx.x;
    const int m0 = blockIdx.y * 128;
    const int n0 = blockIdx.x * 64;
    const int wid = tid >> 6;
    const int lane = tid & 63;
    const int wm = wid >> 1, wn = wid & 1;
    const int l15 = lane & 15, l4 = lane >> 4;

    f32x4 acc[4][2];
#pragma unroll
    for (int i = 0; i < 4; ++i)
#pragma unroll
        for (int j = 0; j < 2; ++j) acc[i][j] = (f32x4){0.f, 0.f, 0.f, 0.f};

    const int arow = tid >> 1, acg = (tid & 1) * 16;
    const int brow = tid >> 2, bcg = (tid & 3) * 8;

    for (int k0 = 0; k0 < K; k0 += 32) {
        const ushort* ag = (const ushort*)A + (size_t)(m0 + arow) * K + k0 + acg;
        bf16x8 a0 = *(const bf16x8*)ag;
        bf16x8 a1 = *(const bf16x8*)(ag + 8);
        const ushort* bg = (const ushort*)B + (size_t)(n0 + brow) * K + k0 + bcg;
        bf16x8 b0 = *(const bf16x8*)bg;
        __syncthreads();   // protect previous iteration's fragment reads
        *(bf16x8*)&As[arow][acg] = a0;
        *(bf16x8*)&As[arow][acg + 8] = a1;
        *(bf16x8*)&Bs[brow][bcg] = b0;
        __syncthreads();
        bf16x8 af[4], bfr[2];
#pragma unroll
        for (int m = 0; m < 4; ++m) af[m] = *(const bf16x8*)&As[wm * 64 + m * 16 + l15][l4 * 8];
#pragma unroll
        for (int n = 0; n < 2; ++n) bfr[n] = *(const bf16x8*)&Bs[wn * 32 + n * 16 + l15][l4 * 8];
#pragma unroll
        for (int m = 0; m < 4; ++m)
#pragma unroll
            for (int n = 0; n < 2; ++n)
                acc[m][n] = __builtin_amdgcn_mfma_f32_16x16x32_bf16(af[m], bfr[n], acc[m][n], 0, 0, 0);
    }

#pragma unroll
    for (int m = 0; m < 4; ++m) {
#pragma unroll
        for (int n = 0; n < 2; ++n) {
            int col = n0 + wn * 32 + n * 16 + l15;
#pragma unroll
            for (int r = 0; r < 4; ++r) {
                int row = m0 + wm * 64 + m * 16 + l4 * 4 + r;
                float v = acc[m][n][r];
                if constexpr (MODE >= 1) v += bias[col];
                if constexpr (MODE == 2) {
                    v = fmaxf(v, 0.f);
                    ((__hip_bfloat16*)Cv)[(size_t)row * N + col] = __float2bfloat16(v);
                } else {
                    ((float*)Cv)[(size_t)row * N + col] = v;
                }
            }
        }
    }
}

// ---------------- FastRNN scan: 32 blocks = (batch, dir), 256 threads, U in VGPRs ------
__global__ __launch_bounds__(256, 1) void scan_kernel(
    const float* __restrict__ pre, const float* __restrict__ Uf, const float* __restrict__ Ub,
    const float* __restrict__ alpha_f, const float* __restrict__ beta_f,
    const float* __restrict__ alpha_b, const float* __restrict__ beta_b,
    __hip_bfloat16* __restrict__ h_out)
{
    const int blk = blockIdx.x;
    const int dir = blk & 1, b = blk >> 1;
    const int d = threadIdx.x;
    const float* U = dir ? Ub : Uf;
    const float alpha = dir ? alpha_b[0] : alpha_f[0];
    const float beta  = dir ? beta_b[0]  : beta_f[0];
    const float a  = 1.f / (1.f + __expf(-alpha));
    const float bb = 1.f / (1.f + __expf(-beta));

    float4 u[64];
    const float4* Urow = (const float4*)(U + d * 256);
#pragma unroll
    for (int i = 0; i < 64; ++i) u[i] = Urow[i];

    __shared__ __align__(16) float hbuf[2][256];
    hbuf[0][d] = 0.f;
    __syncthreads();

    float h_own = 0.f;
    const float* preb = pre + ((size_t)b * 4096) * 512 + dir * 256 + d;
    __hip_bfloat16* hop = h_out + ((size_t)b * 4096) * 512 + dir * 256 + d;

    int s0 = dir ? 4095 : 0;
    float p_cur = preb[(size_t)s0 * 512];

    for (int t = 0; t < 4096; ++t) {
        int tn = (t < 4095) ? (t + 1) : t;
        int s_next = dir ? (4095 - tn) : tn;
        float p_next = preb[(size_t)s_next * 512];

        int cur = t & 1;
        const float4* hb = (const float4*)hbuf[cur];
        float acc0 = 0.f, acc1 = 0.f, acc2 = 0.f, acc3 = 0.f;
        float4 hreg[8];
#pragma unroll
        for (int i = 0; i < 8; ++i) hreg[i] = hb[i];
#pragma unroll
        for (int i = 0; i < 64; ++i) {
            float4 h4 = hreg[i & 7];
            if (i + 8 < 64) hreg[i & 7] = hb[i + 8];
            acc0 = fmaf(h4.x, u[i].x, acc0);
            acc1 = fmaf(h4.y, u[i].y, acc1);
            acc2 = fmaf(h4.z, u[i].z, acc2);
            acc3 = fmaf(h4.w, u[i].w, acc3);
        }
        float z = p_cur + ((acc0 + acc1) + (acc2 + acc3));
        float e = __expf(z + z);
        float th = 1.f - 2.f * __builtin_amdgcn_rcpf(e + 1.f);
        float hn = fmaf(a, th, bb * h_own);
        h_own = hn;
        hbuf[cur ^ 1][d] = hn;
        int s = dir ? (4095 - t) : t;
        hop[(size_t)s * 512] = __float2bfloat16(hn);
        __syncthreads();
        p_cur = p_next;
    }
}

// ---------------- epilogue: out2 (tokens x 128 f32) -> d_out transposed layout ---------
__global__ __launch_bounds__(256) void epi_kernel(
    const float* __restrict__ out2, const float* __restrict__ b2cat, float* __restrict__ out)
{
    __shared__ float tile[64][129];
    const int t0 = blockIdx.x * 64;
    const int tid = threadIdx.x;
#pragma unroll
    for (int i = 0; i < 32; ++i) {
        int idx = tid + i * 256;
        int tk = idx >> 7, j = idx & 127;
        tile[tk][j] = out2[((size_t)(t0 + tk)) * 128 + j];
    }
    __syncthreads();
    for (int p = 0; p < 22; ++p) {
        int idx = tid + p * 256;
        if (idx < 5440) {
            int j = idx >> 6;        // 0..84
            int s_ = idx & 63;
            float v = tile[s_][j] + b2cat[j];
            int token = t0 + s_;
            int b = token >> 12, s = token & 4095;
            size_t dst;
            if (j < 80) {
                dst = (size_t)b * 327680 + (size_t)j * 4096 + s;
            } else if (j < 84) {
                v = fmaxf(v, 0.f);
                dst = 5242880 + (size_t)b * 16384 + (size_t)(j - 80) * 4096 + s;
            } else {
                dst = 5505024 + (size_t)b * 4096 + s;
            }
            out[dst] = v;
        }
    }
}

extern "C" void kernel_launch(void* const* d_in, const int* in_sizes, int n_in,
                              void* d_out, int out_size, void* d_ws, size_t ws_size,
                              hipStream_t stream) {
    (void)in_sizes; (void)n_in; (void)out_size; (void)ws_size;
    const float* feat    = (const float*)d_in[0];
    const float* proj_w  = (const float*)d_in[1];
    const float* proj_b  = (const float*)d_in[2];
    const float* Wf      = (const float*)d_in[3];
    const float* Uf      = (const float*)d_in[4];
    const float* bf_     = (const float*)d_in[5];
    const float* alpha_f = (const float*)d_in[6];
    const float* beta_f  = (const float*)d_in[7];
    const float* Wb      = (const float*)d_in[8];
    const float* Ub      = (const float*)d_in[9];
    const float* bb_     = (const float*)d_in[10];
    const float* alpha_b = (const float*)d_in[11];
    const float* beta_b  = (const float*)d_in[12];
    const float* cls_w1  = (const float*)d_in[13];
    const float* cls_b1  = (const float*)d_in[14];
    const float* cls_w2  = (const float*)d_in[15];
    const float* cls_b2  = (const float*)d_in[16];
    const float* reg_w1  = (const float*)d_in[17];
    const float* reg_b1  = (const float*)d_in[18];
    const float* reg_w2  = (const float*)d_in[19];
    const float* reg_b2  = (const float*)d_in[20];
    const float* ctr_w1  = (const float*)d_in[21];
    const float* ctr_b1  = (const float*)d_in[22];
    const float* ctr_w2  = (const float*)d_in[23];
    const float* ctr_b2  = (const float*)d_in[24];

    // workspace layout (total ~262.3 MB)
    char* ws = (char*)d_ws;
    __hip_bfloat16* h_bf  = (__hip_bfloat16*)(ws);                 // 67,108,864
    float*          pre   = (float*)(ws + 67108864);               // 134,217,728
    char*           regC  = ws + 201326592;                        // 58,720,256 shared region
    __hip_bfloat16* fx    = (__hip_bfloat16*)regC;                 // 33,554,432 (phase 1)
    __hip_bfloat16* L1c   = (__hip_bfloat16*)regC;                 // 25,165,824 (phase 3)
    float*          out2  = (float*)(regC + 25165824);             // 33,554,432 (phase 3)
    char*           wts   = ws + 260046848;
    __hip_bfloat16* Mcat  = (__hip_bfloat16*)(wts);                // 262,144
    float*          cvec  = (float*)(wts + 262144);                // 2,048
    __hip_bfloat16* W1cat = (__hip_bfloat16*)(wts + 264192);       // 1,572,864
    float*          b1cat = (float*)(wts + 1837056);               // 6,144
    __hip_bfloat16* W2pad = (__hip_bfloat16*)(wts + 1843200);      // 393,216
    float*          b2cat = (float*)(wts + 2236416);               // 384

    prep_mcat<<<512, 256, 0, stream>>>(proj_w, proj_b, Wf, bf_, Wb, bb_, Mcat, cvec);
    prep_weights<<<3072, 256, 0, stream>>>(cls_w1, cls_b1, cls_w2, cls_b2,
        reg_w1, reg_b1, reg_w2, reg_b2, ctr_w1, ctr_b1, ctr_w2, ctr_b2,
        W1cat, b1cat, W2pad, b2cat);
    transpose_feat<<<dim3(64, 8, 16), 256, 0, stream>>>(feat, fx);

    // pre[token, 0:256]=fwd pre, [256:512]=bwd pre (f32)
    gemm_bf16<1><<<dim3(8, 512), 256, 0, stream>>>(fx, Mcat, pre, cvec, 65536, 512, 256);

    scan_kernel<<<32, 256, 0, stream>>>(pre, Uf, Ub, alpha_f, beta_f, alpha_b, beta_b, h_bf);

    for (int c = 0; c < 8; ++c) {
        gemm_bf16<2><<<dim3(24, 64), 256, 0, stream>>>(
            h_bf + (size_t)c * 8192 * 512, W1cat, L1c, b1cat, 8192, 1536, 512);
        gemm_bf16<0><<<dim3(2, 64), 256, 0, stream>>>(
            L1c, W2pad, out2 + (size_t)c * 8192 * 128, nullptr, 8192, 128, 1536);
    }

    epi_kernel<<<1024, 256, 0, stream>>>(out2, b2cat, (float*)d_out);
}